// Round 1
// baseline (1443.335 us; speedup 1.0000x reference)
//
#include <hip/hip_runtime.h>
#include <hip/hip_bf16.h>
#include <math.h>

// Problem shape (fixed by reference setup_inputs)
#define NQ    32      // queries per batch
#define DIM   128     // embedding dim
#define NDOC  2048    // docs per batch
#define NWAVE 4       // waves per block
#define TILE  32      // docs per MFMA tile (N of 32x32x16)

typedef __attribute__((ext_vector_type(8)))  short bf16x8;   // MFMA A/B frag (8 bf16)
typedef __attribute__((ext_vector_type(16))) float f32x16;   // MFMA C/D frag

// fp32 -> bf16 round-to-nearest-even, returned as raw 16-bit pattern
__device__ __forceinline__ short f2bf(float x) {
    unsigned u = __builtin_bit_cast(unsigned, x);
    u += 0x7fffu + ((u >> 16) & 1u);
    return (short)(u >> 16);
}

__global__ __launch_bounds__(256) void maxsim_kernel(
        const float* __restrict__ Q,   // [B, NQ, DIM]
        const float* __restrict__ Dc,  // [B, NDOC, DIM]
        float* __restrict__ out)       // [B]
{
    const int b   = blockIdx.x;
    const int tid = threadIdx.x;
    const int lane = tid & 63;
    const int wave = tid >> 6;

    const float* qb = Q  + (size_t)b * NQ   * DIM;
    const float* db = Dc + (size_t)b * NDOC * DIM;

    __shared__ __hip_bfloat16 qs[NQ][DIM];        // normalized queries, bf16 (8 KiB)
    __shared__ float          smax[NWAVE][NQ];    // per-wave per-query maxes

    // ---- Phase 1: load + L2-normalize queries, store bf16 to LDS ----
    // 256 threads: row r = tid>>3 (8 threads/row), each handles 16 contiguous cols.
    {
        const int r  = tid >> 3;
        const int c0 = (tid & 7) * 16;
        const float* qr = qb + r * DIM + c0;
        float4 v0 = *(const float4*)(qr + 0);
        float4 v1 = *(const float4*)(qr + 4);
        float4 v2 = *(const float4*)(qr + 8);
        float4 v3 = *(const float4*)(qr + 12);
        float ss = v0.x*v0.x + v0.y*v0.y + v0.z*v0.z + v0.w*v0.w
                 + v1.x*v1.x + v1.y*v1.y + v1.z*v1.z + v1.w*v1.w
                 + v2.x*v2.x + v2.y*v2.y + v2.z*v2.z + v2.w*v2.w
                 + v3.x*v3.x + v3.y*v3.y + v3.z*v3.z + v3.w*v3.w;
        // reduce across the 8 threads of this row (lanes grouped 8-consecutive)
        ss += __shfl_xor(ss, 1);
        ss += __shfl_xor(ss, 2);
        ss += __shfl_xor(ss, 4);
        const float inv = rsqrtf(fmaxf(ss, 1e-24f));  // matches max(||x||,1e-12)
        const float* vv[4] = { nullptr, nullptr, nullptr, nullptr };
        (void)vv;
        float tmp[16] = { v0.x,v0.y,v0.z,v0.w, v1.x,v1.y,v1.z,v1.w,
                          v2.x,v2.y,v2.z,v2.w, v3.x,v3.y,v3.z,v3.w };
        #pragma unroll
        for (int j = 0; j < 16; ++j) {
            short h = f2bf(tmp[j] * inv);
            qs[r][c0 + j] = __builtin_bit_cast(__hip_bfloat16, h);
        }
    }
    __syncthreads();

    // ---- Phase 2: load A-fragments (all K=128) into registers, kept for whole loop ----
    // A layout for v_mfma_f32_32x32x16_bf16: lane holds row m=lane&31,
    // k = (lane>>5)*8 + j within each K=16 step.
    bf16x8 afrag[8];
    {
        const int am = lane & 31;
        const int ak = (lane >> 5) * 8;
        #pragma unroll
        for (int kk = 0; kk < 8; ++kk)
            afrag[kk] = *(const bf16x8*)(&qs[am][ak + kk * 16]);
    }

    // ---- Phase 3: stream doc tiles, MFMA, running max ----
    float runmax[16];
    #pragma unroll
    for (int i = 0; i < 16; ++i) runmax[i] = -INFINITY;

    const int koff = (lane >> 5) * 8;  // this lane's k-subblock within each K=16
    for (int t = wave; t < NDOC / TILE; t += NWAVE) {
        // lane loads doc n = lane&31 of this tile, 8 contiguous fp32 per k-step
        const float* dl = db + (size_t)t * TILE * DIM + (size_t)(lane & 31) * DIM + koff;
        f32x16 acc = {};
        float ss = 0.0f;
        #pragma unroll
        for (int kk = 0; kk < 8; ++kk) {
            float4 u0 = *(const float4*)(dl + kk * 16);
            float4 u1 = *(const float4*)(dl + kk * 16 + 4);
            ss += u0.x*u0.x + u0.y*u0.y + u0.z*u0.z + u0.w*u0.w
                + u1.x*u1.x + u1.y*u1.y + u1.z*u1.z + u1.w*u1.w;
            bf16x8 bfrag;
            bfrag[0] = f2bf(u0.x); bfrag[1] = f2bf(u0.y);
            bfrag[2] = f2bf(u0.z); bfrag[3] = f2bf(u0.w);
            bfrag[4] = f2bf(u1.x); bfrag[5] = f2bf(u1.y);
            bfrag[6] = f2bf(u1.z); bfrag[7] = f2bf(u1.w);
            acc = __builtin_amdgcn_mfma_f32_32x32x16_bf16(afrag[kk], bfrag, acc, 0, 0, 0);
        }
        // combine the two k-halves of the doc self-dot (lanes l and l+32 share doc)
        ss += __shfl_xor(ss, 32);
        const float invd = rsqrtf(fmaxf(ss, 1e-24f));
        // C layout: col = lane&31 == this lane's doc; scale by 1/||d|| then max
        #pragma unroll
        for (int i = 0; i < 16; ++i)
            runmax[i] = fmaxf(runmax[i], acc[i] * invd);
    }

    // ---- Phase 4: max across the 32 columns (docs) held per half-wave ----
    #pragma unroll
    for (int i = 0; i < 16; ++i) {
        float v = runmax[i];
        v = fmaxf(v, __shfl_xor(v, 1));
        v = fmaxf(v, __shfl_xor(v, 2));
        v = fmaxf(v, __shfl_xor(v, 4));
        v = fmaxf(v, __shfl_xor(v, 8));
        v = fmaxf(v, __shfl_xor(v, 16));
        runmax[i] = v;
    }
    // C layout rows: row = (i&3) + 8*(i>>2) + 4*(lane>>5)
    if ((lane & 31) == 0) {
        const int h = lane >> 5;
        #pragma unroll
        for (int i = 0; i < 16; ++i) {
            const int row = (i & 3) + 8 * (i >> 2) + 4 * h;
            smax[wave][row] = runmax[i];
        }
    }
    __syncthreads();

    // ---- Phase 5: combine waves, sum over queries, write score ----
    if (tid < 32) {
        float m = smax[0][tid];
        #pragma unroll
        for (int w = 1; w < NWAVE; ++w) m = fmaxf(m, smax[w][tid]);
        m += __shfl_xor(m, 1);
        m += __shfl_xor(m, 2);
        m += __shfl_xor(m, 4);
        m += __shfl_xor(m, 8);
        m += __shfl_xor(m, 16);
        if (tid == 0) out[b] = m;
    }
}

extern "C" void kernel_launch(void* const* d_in, const int* in_sizes, int n_in,
                              void* d_out, int out_size, void* d_ws, size_t ws_size,
                              hipStream_t stream) {
    const float* q = (const float*)d_in[0];
    const float* d = (const float*)d_in[1];
    float* out = (float*)d_out;
    const int B = in_sizes[0] / (NQ * DIM);  // 1024
    maxsim_kernel<<<dim3(B), dim3(256), 0, stream>>>(q, d, out);
}